// Round 11
// baseline (99.928 us; speedup 1.0000x reference)
//
#include <hip/hip_runtime.h>

typedef __attribute__((ext_vector_type(8))) short short8;
typedef __attribute__((ext_vector_type(4))) float f32x4;
typedef unsigned short u16;
typedef unsigned int u32;

#define NNODES 65536
#define FDIM 128

__device__ __forceinline__ u16 f2bf(float f) {
    u32 u = __float_as_uint(f);
    u32 r = (u + 0x7fffu + ((u >> 16) & 1u)) >> 16;   // RNE
    return (u16)r;
}
__device__ __forceinline__ u32 pack2bf(float lo, float hi) {
    return ((u32)f2bf(hi) << 16) | f2bf(lo);
}
__device__ __forceinline__ float bf2f(short s) {
    return __uint_as_float(((u32)(u16)s) << 16);
}

// ---------- fused prep: rowptr + wT casts + x cast, partitioned by blockIdx ----------
__global__ void prep_kernel(const int* __restrict__ erow, int* __restrict__ rowptr,
                            const float* __restrict__ w1, u16* __restrict__ wt1,
                            const float* __restrict__ w2, u16* __restrict__ wt2,
                            const float* __restrict__ w3, u16* __restrict__ wt3,
                            const float* __restrict__ x, u16* __restrict__ xb,
                            int n, int e) {
    const int b = blockIdx.x;
    const int tid = threadIdx.x;
    if (b < 257) {                               // rowptr
        int r = b * 256 + tid;
        if (r > n) return;
        int lo = 0, hi = e;
        while (lo < hi) {
            int mid = (lo + hi) >> 1;
            if (erow[mid] < r) lo = mid + 1; else hi = mid;
        }
        rowptr[r] = lo;
    } else if (b < 417) {                        // weight transpose-cast
        const float* w; u16* wt; int idx;
        if (b < 321)      { w = w1; wt = wt1; idx = (b - 257) * 256 + tid; }
        else if (b < 385) { w = w2; wt = wt2; idx = (b - 321) * 256 + tid; }
        else              { w = w3; wt = wt3; idx = (b - 385) * 256 + tid; }
        const int K = 128;
        const int NC = (b < 385) ? 128 : 64;
        if (idx >= K * NC) return;
        int nn = idx / K, k = idx - nn * K;
        wt[idx] = f2bf(w[k * NC + nn]);
    } else {                                     // x -> bf16 (uint2 per thread)
        int i = (b - 417) * 256 + tid;
        if (i >= n * FDIM / 4) return;
        float4 v = reinterpret_cast<const float4*>(x)[i];
        uint2 p;
        p.x = pack2bf(v.x, v.y);
        p.y = pack2bf(v.z, v.w);
        reinterpret_cast<uint2*>(xb)[i] = p;
    }
}

// ---------- Fused SpMM + GEMM(s), 16 rows / 8 waves per block ----------
// R9 post-mortem fix: each wave runs EXACTLY R7's 2-row pipeline once (no
// serial it-loop), 512-thread blocks keep wave count at 32768 and 24 waves/CU
// (launch_bounds(512,6) = 3 blocks/CU). SpMM result tile lands in LDS
// (stride 136), one barrier, then 8 waves x 1 col-tile MFMA vs register-held
// weight frags (L2-hot). LAYER 2 chains gemm2 -> relu -> LDS -> gemm3 -> fp32.
template<int LAYER>
__global__ __launch_bounds__(512, 6)
void fused_kernel(const u16* __restrict__ h, const int* __restrict__ rowptr,
                  const int* __restrict__ col, const float* __restrict__ val,
                  const u16* __restrict__ WA, const u16* __restrict__ WB,
                  void* __restrict__ outp, int n) {
    constexpr int LSTR = 136;                    // u16 stride: 128 data + 8 pad
    __shared__ u16 ytile[16 * LSTR];             // spmm result tile (bf16)
    __shared__ u16 h2tile[LAYER == 2 ? 16 * LSTR : 1];

    const int t = threadIdx.x;
    const int wave = t >> 6;                     // 0..7
    const int lane = t & 63;
    const int slot = lane >> 4;
    const int fg = lane & 15;
    const int R0 = blockIdx.x * 16;
    const u16* hf = h + fg * 8;

    // ================= SpMM phase (R7 2-row pipeline, one pass) =================
    {
        const int rA = R0 + wave * 2;
        const int sA = rowptr[rA], eA = rowptr[rA + 1], eB = rowptr[rA + 2];

        int iA = sA + slot;
        int c0A = 0, c1A = 0; float v0A = 0.f, v1A = 0.f;
        if (iA < eA)     { c0A = col[iA];     v0A = val[iA]; }
        if (iA + 4 < eA) { c1A = col[iA + 4]; v1A = val[iA + 4]; }
        int iB = eA + slot;
        int c0B = 0, c1B = 0; float v0B = 0.f, v1B = 0.f;
        if (iB < eB)     { c0B = col[iB];     v0B = val[iB]; }
        if (iB + 4 < eB) { c1B = col[iB + 4]; v1B = val[iB + 4]; }

        short8 g0A = *reinterpret_cast<const short8*>(hf + (size_t)c0A * FDIM);
        short8 g1A = *reinterpret_cast<const short8*>(hf + (size_t)c1A * FDIM);
        short8 g0B = *reinterpret_cast<const short8*>(hf + (size_t)c0B * FDIM);
        short8 g1B = *reinterpret_cast<const short8*>(hf + (size_t)c1B * FDIM);

        int jA = iA + 8;
        int c2A = 0, c3A = 0; float v2A = 0.f, v3A = 0.f;
        if (jA < eA)     { c2A = col[jA];     v2A = val[jA]; }
        if (jA + 4 < eA) { c3A = col[jA + 4]; v3A = val[jA + 4]; }
        int jB = iB + 8;
        int c2B = 0, c3B = 0; float v2B = 0.f, v3B = 0.f;
        if (jB < eB)     { c2B = col[jB];     v2B = val[jB]; }
        if (jB + 4 < eB) { c3B = col[jB + 4]; v3B = val[jB + 4]; }

        float accA[8], accB[8];
#pragma unroll
        for (int j = 0; j < 8; ++j) { accA[j] = 0.f; accB[j] = 0.f; }

#pragma unroll
        for (int j = 0; j < 8; ++j) accA[j] = fmaf(v0A, bf2f(g0A[j]), accA[j]);
#pragma unroll
        for (int j = 0; j < 8; ++j) accA[j] = fmaf(v1A, bf2f(g1A[j]), accA[j]);
#pragma unroll
        for (int j = 0; j < 8; ++j) accB[j] = fmaf(v0B, bf2f(g0B[j]), accB[j]);
#pragma unroll
        for (int j = 0; j < 8; ++j) accB[j] = fmaf(v1B, bf2f(g1B[j]), accB[j]);

        while (jA < eA) {
            short8 g0 = *reinterpret_cast<const short8*>(hf + (size_t)c2A * FDIM);
            short8 g1 = *reinterpret_cast<const short8*>(hf + (size_t)c3A * FDIM);
            float v0 = v2A, v1 = v3A;
            jA += 8;
            c2A = 0; c3A = 0; v2A = 0.f; v3A = 0.f;
            if (jA < eA)     { c2A = col[jA];     v2A = val[jA]; }
            if (jA + 4 < eA) { c3A = col[jA + 4]; v3A = val[jA + 4]; }
#pragma unroll
            for (int j = 0; j < 8; ++j) accA[j] = fmaf(v0, bf2f(g0[j]), accA[j]);
#pragma unroll
            for (int j = 0; j < 8; ++j) accA[j] = fmaf(v1, bf2f(g1[j]), accA[j]);
        }
        while (jB < eB) {
            short8 g0 = *reinterpret_cast<const short8*>(hf + (size_t)c2B * FDIM);
            short8 g1 = *reinterpret_cast<const short8*>(hf + (size_t)c3B * FDIM);
            float v0 = v2B, v1 = v3B;
            jB += 8;
            c2B = 0; c3B = 0; v2B = 0.f; v3B = 0.f;
            if (jB < eB)     { c2B = col[jB];     v2B = val[jB]; }
            if (jB + 4 < eB) { c3B = col[jB + 4]; v3B = val[jB + 4]; }
#pragma unroll
            for (int j = 0; j < 8; ++j) accB[j] = fmaf(v0, bf2f(g0[j]), accB[j]);
#pragma unroll
            for (int j = 0; j < 8; ++j) accB[j] = fmaf(v1, bf2f(g1[j]), accB[j]);
        }

#pragma unroll
        for (int m = 16; m <= 32; m <<= 1) {
#pragma unroll
            for (int j = 0; j < 8; ++j) {
                accA[j] += __shfl_xor(accA[j], m, 64);
                accB[j] += __shfl_xor(accB[j], m, 64);
            }
        }

        float a0 = 0.f, a1 = 0.f, b0 = 0.f, b1 = 0.f;
#pragma unroll
        for (int ss = 0; ss < 4; ++ss)
            if (slot == ss) {
                a0 = accA[ss * 2]; a1 = accA[ss * 2 + 1];
                b0 = accB[ss * 2]; b1 = accB[ss * 2 + 1];
            }
        const int rloc = wave * 2;
        *reinterpret_cast<u32*>(&ytile[rloc * LSTR + fg * 8 + slot * 2]) = pack2bf(a0, a1);
        *reinterpret_cast<u32*>(&ytile[(rloc + 1) * LSTR + fg * 8 + slot * 2]) = pack2bf(b0, b1);
    }
    __syncthreads();

    // ================= GEMM phase =================
    const int dn = lane & 15;
    const int kg = lane >> 4;

    // gemm vs WA (w1 or w2): wave handles col-tile nt = wave (cols wave*16..+15)
    short8 bw[4];
#pragma unroll
    for (int s = 0; s < 4; ++s)
        bw[s] = *reinterpret_cast<const short8*>(
            &WA[(size_t)(wave * 16 + dn) * 128 + s * 32 + kg * 8]);

    f32x4 acc = (f32x4){0.f, 0.f, 0.f, 0.f};
#pragma unroll
    for (int s = 0; s < 4; ++s) {
        short8 a = *reinterpret_cast<const short8*>(&ytile[dn * LSTR + s * 32 + kg * 8]);
        acc = __builtin_amdgcn_mfma_f32_16x16x32_bf16(bw[s], a, acc, 0, 0, 0);
    }

    float v0 = fmaxf(acc[0], 0.f), v1 = fmaxf(acc[1], 0.f);
    float v2 = fmaxf(acc[2], 0.f), v3 = fmaxf(acc[3], 0.f);
    uint2 p; p.x = pack2bf(v0, v1); p.y = pack2bf(v2, v3);

    if (LAYER == 1) {
        u16* o = (u16*)outp;
        *reinterpret_cast<uint2*>(
            &o[(size_t)(R0 + dn) * 128 + wave * 16 + kg * 4]) = p;
    } else {
        *reinterpret_cast<uint2*>(
            &h2tile[dn * LSTR + wave * 16 + kg * 4]) = p;
        __syncthreads();

        if (wave < 4) {
            // gemm3 vs WB (w3): wave handles out cols wave*16..+15
            short8 bw3[4];
#pragma unroll
            for (int s = 0; s < 4; ++s)
                bw3[s] = *reinterpret_cast<const short8*>(
                    &WB[(size_t)(wave * 16 + dn) * 128 + s * 32 + kg * 8]);

            f32x4 acc3 = (f32x4){0.f, 0.f, 0.f, 0.f};
#pragma unroll
            for (int s = 0; s < 4; ++s) {
                short8 a = *reinterpret_cast<const short8*>(
                    &h2tile[dn * LSTR + s * 32 + kg * 8]);
                acc3 = __builtin_amdgcn_mfma_f32_16x16x32_bf16(bw3[s], a, acc3, 0, 0, 0);
            }
            float* o = (float*)outp;
            *reinterpret_cast<float4*>(&o[(size_t)(R0 + dn) * 64 + wave * 16 + kg * 4]) =
                make_float4(acc3[0], acc3[1], acc3[2], acc3[3]);
        }
    }
}

extern "C" void kernel_launch(void* const* d_in, const int* in_sizes, int n_in,
                              void* d_out, int out_size, void* d_ws, size_t ws_size,
                              hipStream_t stream) {
    const float* x    = (const float*)d_in[0];
    const float* w1   = (const float*)d_in[1];
    const float* w2   = (const float*)d_in[2];
    const float* w3   = (const float*)d_in[3];
    const int*   erow = (const int*)d_in[4];
    const int*   ecol = (const int*)d_in[5];
    const float* eval = (const float*)d_in[6];
    float* out = (float*)d_out;

    const int N = in_sizes[0] / FDIM;
    const int E = in_sizes[4];

    char* ws = (char*)d_ws;
    int* rowptr = (int*)ws;                                  // (N+1)*4
    u16* wt1 = (u16*)(ws + (512 << 10));                     // 32KB
    u16* wt2 = wt1 + 128 * 128;                              // 32KB
    u16* wt3 = wt2 + 128 * 128;                              // 16KB
    u16* xbuf = (u16*)(ws + (1 << 20));                      // 16MB bf16 [N][128]
    u16* hbuf = (u16*)(ws + (18u << 20));                    // 16MB bf16 [N][128]

    const int xblocks = N * FDIM / 4 / 256;                  // 8192
    prep_kernel<<<417 + xblocks, 256, 0, stream>>>(erow, rowptr, w1, wt1, w2, wt2,
                                                   w3, wt3, x, xbuf, N, E);
    // layer 1: h1 = relu(spmm(x) @ w1)
    fused_kernel<1><<<N / 16, 512, 0, stream>>>(xbuf, rowptr, ecol, eval,
                                                wt1, wt1, hbuf, N);
    // layer 2+3: out = relu(spmm(h1) @ w2) @ w3
    fused_kernel<2><<<N / 16, 512, 0, stream>>>(hbuf, rowptr, ecol, eval,
                                                wt2, wt3, (void*)out, N);
}